// Round 1
// baseline (321.986 us; speedup 1.0000x reference)
//
#include <hip/hip_runtime.h>
#include <math.h>

#define Bn 8
#define Nn 4096
#define Dn 512
#define Ln 64

// ---- workspace layout (bytes) ----
#define WS_NVALID 0                      // 8 ints
#define WS_IDX    256                    // B*N ints = 131072 B
#define WS_QK     (WS_IDX + Bn*Nn*4)     // L*D floats
#define WS_WOZ    (WS_QK + Ln*Dn*4)      // L*D floats
#define WS_WOV    (WS_WOZ + Ln*Dn*4)     // D*D floats
#define WS_S      (WS_WOV + Dn*Dn*4)     // B*L*D floats
#define WS_DEN    (WS_S + Bn*Ln*Dn*4)    // B*L floats

// Kernel 1: detect mask element width on-device, then stable-compact valid
// (mask==0) token indices per sample. One block per sample.
__global__ void k1_compact(const unsigned char* __restrict__ maskbytes,
                           int* __restrict__ nvalid, int* __restrict__ idx)
{
    __shared__ int f_ge2, f_b1, f_m123, s_w;
    __shared__ int scanbuf[256];
    int tid = threadIdx.x;
    int b = blockIdx.x;
    if (tid == 0) { f_ge2 = 0; f_b1 = 0; f_m123 = 0; }
    __syncthreads();
    // Scan first B*N bytes (safe for any width >= 1). Values are 0/1-ish.
    int lge2 = 0, lb1 = 0, lm = 0;
    for (int p = tid; p < Bn * Nn; p += 256) {
        unsigned int v = maskbytes[p];
        if (v > 1u) lge2 = 1;
        if (v != 0u) {
            if ((p & 3) == 1) lb1 = 1;
            if ((p & 3) != 0) lm = 1;
        }
    }
    if (lge2) atomicOr(&f_ge2, 1);
    if (lb1)  atomicOr(&f_b1, 1);
    if (lm)   atomicOr(&f_m123, 1);
    __syncthreads();
    if (tid == 0) {
        // float-like values (bytes 0x80/0x3f...) -> 2-byte iff nonzero at p%4==1
        // 0/1-valued -> 1-byte iff nonzero anywhere off 4-byte boundaries
        s_w = f_ge2 ? (f_b1 ? 2 : 4) : (f_m123 ? 1 : 4);
    }
    __syncthreads();
    int w = s_w;

    // chunked stable compaction: thread t owns elements [t*16, t*16+16)
    int base = tid * 16;
    int cnt = 0;
    int validbits[16];
    for (int e = 0; e < 16; e++) {
        int i = base + e;
        size_t byteoff = ((size_t)b * Nn + i) * (size_t)w;
        unsigned int nz = 0;
        for (int q = 0; q < w; q++) nz |= maskbytes[byteoff + q];
        int valid = (nz == 0) ? 1 : 0;   // mask==True means padding/excluded
        validbits[e] = valid;
        cnt += valid;
    }
    scanbuf[tid] = cnt;
    __syncthreads();
    for (int off = 1; off < 256; off <<= 1) {
        int v = (tid >= off) ? scanbuf[tid - off] : 0;
        __syncthreads();
        scanbuf[tid] += v;
        __syncthreads();
    }
    int pos = scanbuf[tid] - cnt;  // exclusive prefix
    for (int e = 0; e < 16; e++) {
        if (validbits[e]) { idx[b * Nn + pos] = base + e; pos++; }
    }
    if (tid == 255) nvalid[b] = scanbuf[255];
}

// Kernel 2: per learned token l: qk[l] = (Wq z_l) @ Wk  and  woz[l] = Wo z_l + bo
__global__ void k2_precompute(const float* __restrict__ z, const float* __restrict__ Wq,
                              const float* __restrict__ Wk, const float* __restrict__ Wo,
                              const float* __restrict__ bo,
                              float* __restrict__ qk, float* __restrict__ woz)
{
    __shared__ float zl[Dn];
    __shared__ float ql[Dn];
    int tid = threadIdx.x;
    int l = blockIdx.x;
    for (int e = tid; e < Dn; e += 256) zl[e] = z[l * Dn + e];
    __syncthreads();
    // q[d] = dot(Wq[d,:], z_l)
    for (int d = tid; d < Dn; d += 256) {
        const float4* wr = (const float4*)(Wq + (size_t)d * Dn);
        float acc = 0.f;
        for (int k = 0; k < Dn / 4; k++) {
            float4 wv = wr[k];
            acc += wv.x * zl[4*k] + wv.y * zl[4*k+1] + wv.z * zl[4*k+2] + wv.w * zl[4*k+3];
        }
        ql[d] = acc;
    }
    __syncthreads();
    // qk[l][j] = sum_d q[d] * Wk[d][j]
    for (int j = tid; j < Dn; j += 256) {
        float acc = 0.f;
        for (int d = 0; d < Dn; d++) acc += ql[d] * Wk[(size_t)d * Dn + j];
        qk[l * Dn + j] = acc;
    }
    // woz[l][j] = dot(Wo[j,:], z_l) + bo[j]
    for (int j = tid; j < Dn; j += 256) {
        const float4* wr = (const float4*)(Wo + (size_t)j * Dn);
        float acc = 0.f;
        for (int k = 0; k < Dn / 4; k++) {
            float4 wv = wr[k];
            acc += wv.x * zl[4*k] + wv.y * zl[4*k+1] + wv.z * zl[4*k+2] + wv.w * zl[4*k+3];
        }
        woz[l * Dn + j] = acc + bo[j];
    }
}

// Kernel 3: Wov = Wo @ Wv  (C[i][j] = sum_k Wo[i][k] * Wv[k][j]); 32x32 tiles
__global__ void k3_wov(const float* __restrict__ Wo, const float* __restrict__ Wv,
                       float* __restrict__ wov)
{
    __shared__ float As[32][33];
    __shared__ float Bs[32][33];
    int tid = threadIdx.x;
    int bi = blockIdx.y, bj = blockIdx.x;
    int colL = tid & 31;
    int row0 = tid >> 5;  // 0..7
    float acc[4] = {0.f, 0.f, 0.f, 0.f};
    for (int k0 = 0; k0 < Dn; k0 += 32) {
        for (int e = tid; e < 1024; e += 256) {
            int r = e >> 5, c = e & 31;
            As[r][c] = Wo[(size_t)(bi * 32 + r) * Dn + k0 + c];
            Bs[r][c] = Wv[(size_t)(k0 + r) * Dn + bj * 32 + c];
        }
        __syncthreads();
        for (int kk = 0; kk < 32; kk++) {
            float bv = Bs[kk][colL];
            #pragma unroll
            for (int rr = 0; rr < 4; rr++)
                acc[rr] += As[row0 + rr * 8][kk] * bv;
        }
        __syncthreads();
    }
    for (int rr = 0; rr < 4; rr++)
        wov[(size_t)(bi * 32 + row0 + rr * 8) * Dn + bj * 32 + colL] = acc[rr];
}

// Kernel 4: main token kernel. One block (4 waves) per (sample, segment).
// Per used token: LayerNorm -> logit = clip(qk[l]·ln / sqrt(D)) -> e=exp(logit),
// accumulate s += e*ln, denom += e. No max-shift needed (logits clipped to ±5).
__global__ void __launch_bounds__(256) k4_tokens(
    const float* __restrict__ feats, const int* __restrict__ idx,
    const int* __restrict__ nvalid, const float* __restrict__ qk,
    float* __restrict__ s_out, float* __restrict__ den_out)
{
    __shared__ float sred[4 * Dn];
    __shared__ float dred[4];
    int tid = threadIdx.x;
    int wv = tid >> 6;
    int lane = tid & 63;
    int b = blockIdx.x / Ln;
    int l = blockIdx.x % Ln;
    int nv = nvalid[b];
    int seg_size = nv / Ln; if (seg_size < 1) seg_size = 1;
    int used = Ln * seg_size; if (used > nv) used = nv;
    int r0 = l * seg_size;
    int r1 = r0 + seg_size; if (r1 > used) r1 = used;

    // preload this segment's query-key vector fragment (8 floats/lane)
    const float4* qk4 = (const float4*)(qk + (size_t)l * Dn + lane * 8);
    float4 qa = qk4[0], qb = qk4[1];
    float qf[8] = {qa.x, qa.y, qa.z, qa.w, qb.x, qb.y, qb.z, qb.w};

    float sacc[8] = {0,0,0,0,0,0,0,0};
    float dacc = 0.f;
    const float inv_d = 1.0f / (float)Dn;
    const float inv_temp = 1.0f / 22.62741699796952f;  // 1/sqrt(512)

    for (int r = r0 + wv; r < r1; r += 4) {
        int t = idx[b * Nn + r];
        const float* row = feats + ((size_t)b * Nn + t) * Dn;
        const float4* r4 = (const float4*)(row + lane * 8);
        float4 xa = r4[0], xb = r4[1];
        float x[8] = {xa.x, xa.y, xa.z, xa.w, xb.x, xb.y, xb.z, xb.w};
        float sum = 0.f, ssq = 0.f;
        #pragma unroll
        for (int j = 0; j < 8; j++) { sum += x[j]; ssq += x[j] * x[j]; }
        #pragma unroll
        for (int off = 32; off > 0; off >>= 1) {
            sum += __shfl_xor(sum, off);
            ssq += __shfl_xor(ssq, off);
        }
        float mu = sum * inv_d;
        float var = ssq * inv_d - mu * mu;
        float rstd = rsqrtf(var + 1e-5f);
        float ln[8];
        float dot = 0.f;
        #pragma unroll
        for (int j = 0; j < 8; j++) { ln[j] = (x[j] - mu) * rstd; dot += ln[j] * qf[j]; }
        #pragma unroll
        for (int off = 32; off > 0; off >>= 1) dot += __shfl_xor(dot, off);
        float logit = dot * inv_temp;
        logit = fminf(5.0f, fmaxf(-5.0f, logit));
        float e = expf(logit);
        #pragma unroll
        for (int j = 0; j < 8; j++) sacc[j] += e * ln[j];
        dacc += e;
    }

    // combine the 4 waves
    #pragma unroll
    for (int j = 0; j < 8; j++) sred[wv * Dn + lane * 8 + j] = sacc[j];
    if (lane == 0) dred[wv] = dacc;
    __syncthreads();
    for (int e = tid; e < Dn; e += 256) {
        float v = sred[e] + sred[Dn + e] + sred[2 * Dn + e] + sred[3 * Dn + e];
        s_out[(size_t)blockIdx.x * Dn + e] = v;
    }
    if (tid == 0) den_out[blockIdx.x] = dred[0] + dred[1] + dred[2] + dred[3];
}

// Kernel 5: out[row][col] = sum_k (s[row][k]/denom[row]) * Wov[col][k] + bo[col]
// with epilogue selects: empty segment -> woz[l], nvalid==0 -> z[l]. 32x32 tiles.
__global__ void k5_final(const float* __restrict__ s, const float* __restrict__ denom,
                         const int* __restrict__ nvalid, const float* __restrict__ wov,
                         const float* __restrict__ woz, const float* __restrict__ z,
                         const float* __restrict__ bo, float* __restrict__ out)
{
    __shared__ float As[32][33];
    __shared__ float Bs[32][33];
    __shared__ float sinv[32];
    __shared__ float sden[32];
    int tid = threadIdx.x;
    int bi = blockIdx.y, bj = blockIdx.x;
    if (tid < 32) {
        float dv = denom[bi * 32 + tid];
        sden[tid] = dv;
        sinv[tid] = (dv > 0.0f) ? 1.0f / dv : 0.0f;
    }
    __syncthreads();
    int colL = tid & 31;
    int row0 = tid >> 5;
    float acc[4] = {0.f, 0.f, 0.f, 0.f};
    for (int k0 = 0; k0 < Dn; k0 += 32) {
        for (int e = tid; e < 1024; e += 256) {
            int r = e >> 5, c = e & 31;
            As[r][c] = s[(size_t)(bi * 32 + r) * Dn + k0 + c] * sinv[r];
            Bs[r][c] = wov[(size_t)(bj * 32 + r) * Dn + k0 + c];
        }
        __syncthreads();
        for (int kk = 0; kk < 32; kk++) {
            float bv = Bs[colL][kk];
            #pragma unroll
            for (int rr = 0; rr < 4; rr++)
                acc[rr] += As[row0 + rr * 8][kk] * bv;
        }
        __syncthreads();
    }
    int col = bj * 32 + colL;
    float bov = bo[col];
    for (int rr = 0; rr < 4; rr++) {
        int rl = row0 + rr * 8;
        int row = bi * 32 + rl;
        int bb = row >> 6, ll = row & 63;
        float v;
        if (nvalid[bb] == 0)        v = z[ll * Dn + col];
        else if (sden[rl] > 0.0f)   v = acc[rr] + bov;
        else                        v = woz[ll * Dn + col];
        out[(size_t)row * Dn + col] = v;
    }
}

extern "C" void kernel_launch(void* const* d_in, const int* in_sizes, int n_in,
                              void* d_out, int out_size, void* d_ws, size_t ws_size,
                              hipStream_t stream) {
    const float* feats = (const float*)d_in[0];
    // d_in[1] = coords: unused by the reference
    const unsigned char* maskb = (const unsigned char*)d_in[2];
    const float* z  = (const float*)d_in[3];
    const float* Wq = (const float*)d_in[4];
    const float* Wk = (const float*)d_in[5];
    const float* Wv = (const float*)d_in[6];
    const float* Wo = (const float*)d_in[7];
    const float* bo = (const float*)d_in[8];
    float* out = (float*)d_out;

    char* ws = (char*)d_ws;
    int*   nvalid = (int*)(ws + WS_NVALID);
    int*   idx    = (int*)(ws + WS_IDX);
    float* qk     = (float*)(ws + WS_QK);
    float* woz    = (float*)(ws + WS_WOZ);
    float* wov    = (float*)(ws + WS_WOV);
    float* sbuf   = (float*)(ws + WS_S);
    float* den    = (float*)(ws + WS_DEN);

    k1_compact<<<Bn, 256, 0, stream>>>(maskb, nvalid, idx);
    k2_precompute<<<Ln, 256, 0, stream>>>(z, Wq, Wk, Wo, bo, qk, woz);
    k3_wov<<<dim3(16, 16), 256, 0, stream>>>(Wo, Wv, wov);
    k4_tokens<<<Bn * Ln, 256, 0, stream>>>(feats, idx, nvalid, qk, sbuf, den);
    k5_final<<<dim3(16, 16), 256, 0, stream>>>(sbuf, den, nvalid, wov, woz, z, bo, out);
}

// Round 2
// 221.185 us; speedup vs baseline: 1.4557x; 1.4557x over previous
//
#include <hip/hip_runtime.h>
#include <math.h>

#define Bn 8
#define Nn 4096
#define Dn 512
#define Ln 64

// ---- workspace layout (bytes) ----
#define WS_NVALID 0                       // 8 ints (pad to 256)
#define WS_IDX    256                     // B*N ints = 131072 B
#define WS_QK     (WS_IDX + Bn*Nn*4)      // L*D floats
#define WS_WOZ    (WS_QK + Ln*Dn*4)       // L*D floats
#define WS_WQK    (WS_WOZ + Ln*Dn*4)      // D*D floats (Wq^T @ Wk)
#define WS_WOV    (WS_WQK + Dn*Dn*4)      // D*D floats (Wo @ Wv)
#define WS_S      (WS_WOV + Dn*Dn*4)      // B*L*D floats
#define WS_DEN    (WS_S + Bn*Ln*Dn*4)     // B*L floats

// ============================================================================
// Kernel P (fused prep): blocks 0..255  -> 32x32 tile of Wqk = Wq^T @ Wk
//                        blocks 256..511-> 32x32 tile of Wov = Wo  @ Wv
//                        blocks 512..519-> per-sample stable mask compaction
// ============================================================================
__global__ void __launch_bounds__(256) kP_prep(
    const float* __restrict__ Wq, const float* __restrict__ Wk,
    const float* __restrict__ Wo, const float* __restrict__ Wv,
    const unsigned char* __restrict__ maskbytes,
    float* __restrict__ wqk, float* __restrict__ wov,
    int* __restrict__ nvalid, int* __restrict__ idx)
{
    __shared__ float As[32][33];
    __shared__ float Bs[32][33];
    __shared__ int scanbuf[256];
    __shared__ int f_ge2, f_b1, f_m123, s_w;

    int tid = threadIdx.x;
    int gb = blockIdx.x;

    if (gb < 512) {
        // ---------------- tiled fp32 GEMM ----------------
        int which = gb >> 8;           // 0: Wqk, 1: Wov
        int t = gb & 255;
        int bi = t >> 4, bj = t & 15;
        int colL = tid & 31;
        int row0 = tid >> 5;           // 0..7
        const float* Bsrc = which ? Wv : Wk;
        float acc[4] = {0.f, 0.f, 0.f, 0.f};
        for (int k0 = 0; k0 < Dn; k0 += 32) {
            for (int e = tid; e < 1024; e += 256) {
                int r = e >> 5, c = e & 31;
                // which==0: As[r][c] = Wq[k0+r][bi*32+c]   (A^T access, coalesced)
                // which==1: As[r][c] = Wo[bi*32+r][k0+c]   (A access, coalesced)
                As[r][c] = which ? Wo[(size_t)(bi * 32 + r) * Dn + k0 + c]
                                 : Wq[(size_t)(k0 + r) * Dn + bi * 32 + c];
                Bs[r][c] = Bsrc[(size_t)(k0 + r) * Dn + bj * 32 + c];
            }
            __syncthreads();
            if (which) {
                for (int kk = 0; kk < 32; kk++) {
                    float bv = Bs[kk][colL];
                    #pragma unroll
                    for (int rr = 0; rr < 4; rr++)
                        acc[rr] += As[row0 + rr * 8][kk] * bv;
                }
            } else {
                for (int kk = 0; kk < 32; kk++) {
                    float bv = Bs[kk][colL];
                    #pragma unroll
                    for (int rr = 0; rr < 4; rr++)
                        acc[rr] += As[kk][row0 + rr * 8] * bv;
                }
            }
            __syncthreads();
        }
        float* dst = which ? wov : wqk;
        for (int rr = 0; rr < 4; rr++)
            dst[(size_t)(bi * 32 + row0 + rr * 8) * Dn + bj * 32 + colL] = acc[rr];
        return;
    }

    // ---------------- mask compaction (one block per sample) ----------------
    int b = gb - 512;
    if (tid == 0) { f_ge2 = 0; f_b1 = 0; f_m123 = 0; }
    __syncthreads();
    // width detection on first 4096 bytes (>=1024 elements for any width)
    int lge2 = 0, lb1 = 0, lm = 0;
    for (int p = tid; p < 4096; p += 256) {
        unsigned int v = maskbytes[p];
        if (v > 1u) lge2 = 1;
        if (v != 0u) {
            if ((p & 3) == 1) lb1 = 1;
            if ((p & 3) != 0) lm = 1;
        }
    }
    if (lge2) atomicOr(&f_ge2, 1);
    if (lb1)  atomicOr(&f_b1, 1);
    if (lm)   atomicOr(&f_m123, 1);
    __syncthreads();
    if (tid == 0) s_w = f_ge2 ? (f_b1 ? 2 : 4) : (f_m123 ? 1 : 4);
    __syncthreads();
    int w = s_w;

    int base = tid * 16;
    int cnt = 0;
    int validbits[16];
    for (int e = 0; e < 16; e++) {
        int i = base + e;
        size_t byteoff = ((size_t)b * Nn + i) * (size_t)w;
        unsigned int nz = 0;
        for (int q = 0; q < w; q++) nz |= maskbytes[byteoff + q];
        int valid = (nz == 0) ? 1 : 0;   // mask==True means padding/excluded
        validbits[e] = valid;
        cnt += valid;
    }
    scanbuf[tid] = cnt;
    __syncthreads();
    for (int off = 1; off < 256; off <<= 1) {
        int v = (tid >= off) ? scanbuf[tid - off] : 0;
        __syncthreads();
        scanbuf[tid] += v;
        __syncthreads();
    }
    int pos = scanbuf[tid] - cnt;  // exclusive prefix
    for (int e = 0; e < 16; e++) {
        if (validbits[e]) { idx[b * Nn + pos] = base + e; pos++; }
    }
    if (tid == 255) nvalid[b] = scanbuf[255];
}

// ============================================================================
// Kernel D: per (l, half): qk[l][j] = z_l @ Wqk[:,j]; woz[l][j] = Wo[j,:]·z_l + bo[j]
// 128 blocks x 256 threads, one (qk, woz) output pair per thread.
// ============================================================================
__global__ void __launch_bounds__(256) kD_lproj(
    const float* __restrict__ z, const float* __restrict__ Wqk,
    const float* __restrict__ Wo, const float* __restrict__ bo,
    float* __restrict__ qk, float* __restrict__ woz)
{
    __shared__ float zl[Dn];
    int tid = threadIdx.x;
    int l = blockIdx.x >> 1;
    int half = blockIdx.x & 1;
    for (int e = tid; e < Dn; e += 256) zl[e] = z[l * Dn + e];
    __syncthreads();
    int j = half * 256 + tid;

    // qk: column walk of Wqk — coalesced across threads, 4 split accumulators
    float a0 = 0.f, a1 = 0.f, a2 = 0.f, a3 = 0.f;
    for (int d = 0; d < Dn; d += 4) {
        a0 += zl[d]     * Wqk[(size_t)(d)     * Dn + j];
        a1 += zl[d + 1] * Wqk[(size_t)(d + 1) * Dn + j];
        a2 += zl[d + 2] * Wqk[(size_t)(d + 2) * Dn + j];
        a3 += zl[d + 3] * Wqk[(size_t)(d + 3) * Dn + j];
    }
    qk[l * Dn + j] = (a0 + a1) + (a2 + a3);

    // woz: row read of Wo[j][:] (L2-resident), 4 float4 accumulators
    const float4* wr = (const float4*)(Wo + (size_t)j * Dn);
    float4 b0 = {0,0,0,0}, b1v = {0,0,0,0};
    for (int k = 0; k < Dn / 8; k++) {
        float4 w0 = wr[2 * k], w1 = wr[2 * k + 1];
        b0.x += w0.x * zl[8*k];     b0.y += w0.y * zl[8*k+1];
        b0.z += w0.z * zl[8*k+2];   b0.w += w0.w * zl[8*k+3];
        b1v.x += w1.x * zl[8*k+4];  b1v.y += w1.y * zl[8*k+5];
        b1v.z += w1.z * zl[8*k+6];  b1v.w += w1.w * zl[8*k+7];
    }
    woz[l * Dn + j] = ((b0.x + b0.y) + (b0.z + b0.w)) +
                      ((b1v.x + b1v.y) + (b1v.z + b1v.w)) + bo[j];
}

// ============================================================================
// Kernel E: token kernel. One block (4 waves) per (sample, segment).
// 2-token ILP per wave to hide gather + shfl-reduction latency.
// ============================================================================
__global__ void __launch_bounds__(256) kE_tokens(
    const float* __restrict__ feats, const int* __restrict__ idx,
    const int* __restrict__ nvalid, const float* __restrict__ qk,
    float* __restrict__ s_out, float* __restrict__ den_out)
{
    __shared__ float sred[4 * Dn];
    __shared__ float dred[4];
    int tid = threadIdx.x;
    int wv = tid >> 6;
    int lane = tid & 63;
    int b = blockIdx.x / Ln;
    int l = blockIdx.x % Ln;
    int nv = nvalid[b];
    int seg_size = nv / Ln; if (seg_size < 1) seg_size = 1;
    int used = Ln * seg_size; if (used > nv) used = nv;
    int r0 = l * seg_size;
    int r1 = r0 + seg_size; if (r1 > used) r1 = used;

    const float4* qk4 = (const float4*)(qk + (size_t)l * Dn + lane * 8);
    float4 qa = qk4[0], qb = qk4[1];
    float qf[8] = {qa.x, qa.y, qa.z, qa.w, qb.x, qb.y, qb.z, qb.w};

    float sacc[8] = {0,0,0,0,0,0,0,0};
    float dacc = 0.f;
    const float inv_d = 1.0f / (float)Dn;
    const float inv_temp = 1.0f / 22.62741699796952f;  // 1/sqrt(512)

    for (int r = r0 + wv * 2; r < r1; r += 8) {
        int has2 = (r + 1 < r1);
        int t0 = idx[b * Nn + r];
        int t1 = has2 ? idx[b * Nn + r + 1] : t0;
        const float4* p0 = (const float4*)(feats + ((size_t)b * Nn + t0) * Dn + lane * 8);
        const float4* p1 = (const float4*)(feats + ((size_t)b * Nn + t1) * Dn + lane * 8);
        float4 xa0 = p0[0], xb0 = p0[1];
        float4 xa1 = p1[0], xb1 = p1[1];
        float x0[8] = {xa0.x, xa0.y, xa0.z, xa0.w, xb0.x, xb0.y, xb0.z, xb0.w};
        float x1[8] = {xa1.x, xa1.y, xa1.z, xa1.w, xb1.x, xb1.y, xb1.z, xb1.w};
        float sum0 = 0.f, ssq0 = 0.f, sum1 = 0.f, ssq1 = 0.f;
        #pragma unroll
        for (int j = 0; j < 8; j++) {
            sum0 += x0[j]; ssq0 += x0[j] * x0[j];
            sum1 += x1[j]; ssq1 += x1[j] * x1[j];
        }
        #pragma unroll
        for (int off = 32; off > 0; off >>= 1) {
            sum0 += __shfl_xor(sum0, off);
            ssq0 += __shfl_xor(ssq0, off);
            sum1 += __shfl_xor(sum1, off);
            ssq1 += __shfl_xor(ssq1, off);
        }
        float mu0 = sum0 * inv_d, mu1 = sum1 * inv_d;
        float rstd0 = rsqrtf(ssq0 * inv_d - mu0 * mu0 + 1e-5f);
        float rstd1 = rsqrtf(ssq1 * inv_d - mu1 * mu1 + 1e-5f);
        float ln0[8], ln1[8];
        float dot0 = 0.f, dot1 = 0.f;
        #pragma unroll
        for (int j = 0; j < 8; j++) {
            ln0[j] = (x0[j] - mu0) * rstd0; dot0 += ln0[j] * qf[j];
            ln1[j] = (x1[j] - mu1) * rstd1; dot1 += ln1[j] * qf[j];
        }
        #pragma unroll
        for (int off = 32; off > 0; off >>= 1) {
            dot0 += __shfl_xor(dot0, off);
            dot1 += __shfl_xor(dot1, off);
        }
        float lg0 = fminf(5.0f, fmaxf(-5.0f, dot0 * inv_temp));
        float lg1 = fminf(5.0f, fmaxf(-5.0f, dot1 * inv_temp));
        float e0 = expf(lg0);
        float e1 = has2 ? expf(lg1) : 0.f;
        #pragma unroll
        for (int j = 0; j < 8; j++) sacc[j] += e0 * ln0[j] + e1 * ln1[j];
        dacc += e0 + e1;
    }

    #pragma unroll
    for (int j = 0; j < 8; j++) sred[wv * Dn + lane * 8 + j] = sacc[j];
    if (lane == 0) dred[wv] = dacc;
    __syncthreads();
    for (int e = tid; e < Dn; e += 256) {
        float v = sred[e] + sred[Dn + e] + sred[2 * Dn + e] + sred[3 * Dn + e];
        s_out[(size_t)blockIdx.x * Dn + e] = v;
    }
    if (tid == 0) den_out[blockIdx.x] = dred[0] + dred[1] + dred[2] + dred[3];
}

// ============================================================================
// Kernel G: out[row][col] = sum_k (s[row][k]/den[row]) * Wov[col][k] + bo[col]
// epilogue: empty segment -> woz[l], nvalid==0 -> z[l]. 32x32 tiles.
// ============================================================================
__global__ void __launch_bounds__(256) kG_final(
    const float* __restrict__ s, const float* __restrict__ denom,
    const int* __restrict__ nvalid, const float* __restrict__ wov,
    const float* __restrict__ woz, const float* __restrict__ z,
    const float* __restrict__ bo, float* __restrict__ out)
{
    __shared__ float As[32][33];
    __shared__ float Bs[32][33];
    __shared__ float sinv[32];
    __shared__ float sden[32];
    int tid = threadIdx.x;
    int bi = blockIdx.y, bj = blockIdx.x;
    if (tid < 32) {
        float dv = denom[bi * 32 + tid];
        sden[tid] = dv;
        sinv[tid] = (dv > 0.0f) ? 1.0f / dv : 0.0f;
    }
    __syncthreads();
    int colL = tid & 31;
    int row0 = tid >> 5;
    float acc[4] = {0.f, 0.f, 0.f, 0.f};
    for (int k0 = 0; k0 < Dn; k0 += 32) {
        for (int e = tid; e < 1024; e += 256) {
            int r = e >> 5, c = e & 31;
            As[r][c] = s[(size_t)(bi * 32 + r) * Dn + k0 + c] * sinv[r];
            Bs[r][c] = wov[(size_t)(bj * 32 + r) * Dn + k0 + c];
        }
        __syncthreads();
        for (int kk = 0; kk < 32; kk++) {
            float bv = Bs[colL][kk];
            #pragma unroll
            for (int rr = 0; rr < 4; rr++)
                acc[rr] += As[row0 + rr * 8][kk] * bv;
        }
        __syncthreads();
    }
    int col = bj * 32 + colL;
    float bov = bo[col];
    for (int rr = 0; rr < 4; rr++) {
        int rl = row0 + rr * 8;
        int row = bi * 32 + rl;
        int bb = row >> 6, ll = row & 63;
        float v;
        if (nvalid[bb] == 0)        v = z[ll * Dn + col];
        else if (sden[rl] > 0.0f)   v = acc[rr] + bov;
        else                        v = woz[ll * Dn + col];
        out[(size_t)row * Dn + col] = v;
    }
}

extern "C" void kernel_launch(void* const* d_in, const int* in_sizes, int n_in,
                              void* d_out, int out_size, void* d_ws, size_t ws_size,
                              hipStream_t stream) {
    const float* feats = (const float*)d_in[0];
    // d_in[1] = coords: unused by the reference
    const unsigned char* maskb = (const unsigned char*)d_in[2];
    const float* z  = (const float*)d_in[3];
    const float* Wq = (const float*)d_in[4];
    const float* Wk = (const float*)d_in[5];
    const float* Wv = (const float*)d_in[6];
    const float* Wo = (const float*)d_in[7];
    const float* bo = (const float*)d_in[8];
    float* out = (float*)d_out;

    char* ws = (char*)d_ws;
    int*   nvalid = (int*)(ws + WS_NVALID);
    int*   idx    = (int*)(ws + WS_IDX);
    float* qk     = (float*)(ws + WS_QK);
    float* woz    = (float*)(ws + WS_WOZ);
    float* wqk    = (float*)(ws + WS_WQK);
    float* wov    = (float*)(ws + WS_WOV);
    float* sbuf   = (float*)(ws + WS_S);
    float* den    = (float*)(ws + WS_DEN);

    kP_prep<<<520, 256, 0, stream>>>(Wq, Wk, Wo, Wv, maskb, wqk, wov, nvalid, idx);
    kD_lproj<<<128, 256, 0, stream>>>(z, wqk, Wo, bo, qk, woz);
    kE_tokens<<<Bn * Ln, 256, 0, stream>>>(feats, idx, nvalid, qk, sbuf, den);
    kG_final<<<dim3(16, 16), 256, 0, stream>>>(sbuf, den, nvalid, wov, woz, z, bo, out);
}

// Round 3
// 147.167 us; speedup vs baseline: 2.1879x; 1.5030x over previous
//
#include <hip/hip_runtime.h>
#include <math.h>

#define Bn 8
#define Nn 4096
#define Dn 512
#define Ln 64

// ---------------------------------------------------------------------------
// Shared-memory-tiled fp32 GEMM building block.
//   C_tile(64 x TN) += A[m0.., kbase..kbase+16*ksteps) @ Beff
//   A: row-major [M][512], k-contiguous. NPART>1: A is NPART partials
//      (stride apstride floats) summed during staging.
//   BT=false: Beff[k][n] = B[k*512 + n]   (direct stage)
//   BT=true : Beff[k][n] = B[n*512 + k]   (transpose stage)
//   SCALE: multiply A row r by sv[r] (shared) during staging.
//   dst: row-major [.][512] partial-output buffer, written at (m0+i, n0+j).
// 256 threads, micro-tile 4 x (TN/16).
// ---------------------------------------------------------------------------
template<int TN, bool BT, int NPART, bool SCALE>
__device__ __forceinline__ void gemm_tile(
    const float* __restrict__ A, size_t apstride, int m0,
    const float* __restrict__ B, int n0, int kbase, int ksteps,
    const float* __restrict__ sv,
    float* __restrict__ dst,
    float (*As)[68], float (*Bs)[132], int tid)
{
    const int ty = tid >> 4;   // 0..15 -> rows ty*4..ty*4+3
    const int tx = tid & 15;   // 0..15 -> cols tx*(TN/16)..
    float acc[4][TN / 16];
    #pragma unroll
    for (int m = 0; m < 4; m++)
        #pragma unroll
        for (int n = 0; n < TN / 16; n++) acc[m][n] = 0.f;

    for (int s = 0; s < ksteps; s++) {
        const int k0 = kbase + s * 16;
        // ---- stage A (64 rows x 16 k), transposed into As[kk][row] ----
        {
            int r = tid >> 2, kq = tid & 3;
            float4 v = *(const float4*)&A[(size_t)(m0 + r) * Dn + k0 + kq * 4];
            #pragma unroll
            for (int p = 1; p < NPART; p++) {
                float4 w = *(const float4*)&A[(size_t)p * apstride +
                                              (size_t)(m0 + r) * Dn + k0 + kq * 4];
                v.x += w.x; v.y += w.y; v.z += w.z; v.w += w.w;
            }
            if (SCALE) { float sc = sv[r]; v.x *= sc; v.y *= sc; v.z *= sc; v.w *= sc; }
            As[kq * 4 + 0][r] = v.x;
            As[kq * 4 + 1][r] = v.y;
            As[kq * 4 + 2][r] = v.z;
            As[kq * 4 + 3][r] = v.w;
        }
        // ---- stage B (16 k x TN cols) ----
        #pragma unroll
        for (int rep = 0; rep < TN / 64; rep++) {
            int lin = tid + rep * 256;
            if (!BT) {
                int kk = lin / (TN / 4), jq = lin % (TN / 4);
                *(float4*)&Bs[kk][jq * 4] =
                    *(const float4*)&B[(size_t)(k0 + kk) * Dn + n0 + jq * 4];
            } else {
                int j = lin >> 2, kq = lin & 3;
                float4 v = *(const float4*)&B[(size_t)(n0 + j) * Dn + k0 + kq * 4];
                Bs[kq * 4 + 0][j] = v.x;
                Bs[kq * 4 + 1][j] = v.y;
                Bs[kq * 4 + 2][j] = v.z;
                Bs[kq * 4 + 3][j] = v.w;
            }
        }
        __syncthreads();
        // ---- inner product ----
        #pragma unroll
        for (int kk = 0; kk < 16; kk++) {
            float4 a = *(const float4*)&As[kk][ty * 4];
            float av[4] = {a.x, a.y, a.z, a.w};
            if (TN == 64) {
                float4 b = *(const float4*)&Bs[kk][tx * 4];
                float bv[4] = {b.x, b.y, b.z, b.w};
                #pragma unroll
                for (int m = 0; m < 4; m++)
                    #pragma unroll
                    for (int n = 0; n < 4; n++) acc[m][n] += av[m] * bv[n];
            } else {
                float4 b0 = *(const float4*)&Bs[kk][tx * 8];
                float4 b1 = *(const float4*)&Bs[kk][tx * 8 + 4];
                float bv[8] = {b0.x, b0.y, b0.z, b0.w, b1.x, b1.y, b1.z, b1.w};
                #pragma unroll
                for (int m = 0; m < 4; m++)
                    #pragma unroll
                    for (int n = 0; n < 8; n++) acc[m][n % (TN/16)] += av[m] * bv[n];
            }
        }
        __syncthreads();
    }
    // ---- write partial tile ----
    #pragma unroll
    for (int m = 0; m < 4; m++) {
        size_t base = (size_t)(m0 + ty * 4 + m) * Dn + n0;
        if (TN == 64) {
            float4 o = {acc[m][0], acc[m][1], acc[m][2], acc[m][3]};
            *(float4*)&dst[base + tx * 4] = o;
        } else {
            float4 o0 = {acc[m][0], acc[m][1], acc[m][2], acc[m][3]};
            float4 o1 = {acc[m][4], acc[m][5], acc[m][6], acc[m][7]};
            *(float4*)&dst[base + tx * 8] = o0;
            *(float4*)&dst[base + tx * 8 + 4] = o1;
        }
    }
}

// ============================================================================
// kA: blocks 0..255   : Wov partials wp[8] = Wo @ Wv  (64x128 tiles, Ksplit8)
//     blocks 256..287 : q partials qp[4] = z @ Wq^T   (64x64 tiles, Ksplit4)
//     blocks 288..319 : woz partials wozp[4] = z @ Wo^T
//     blocks 320..327 : per-sample stable mask compaction
// ============================================================================
__global__ void __launch_bounds__(256) kA_prep(
    const float* __restrict__ Wo, const float* __restrict__ Wv,
    const float* __restrict__ z,  const float* __restrict__ Wq,
    const unsigned char* __restrict__ maskbytes,
    float* __restrict__ wp, float* __restrict__ qp, float* __restrict__ wozp,
    int* __restrict__ nvalid, int* __restrict__ idx)
{
    __shared__ float As[16][68];
    __shared__ float Bs[16][132];
    __shared__ int scanbuf[256];
    __shared__ int cflags[4];   // f_ge2, f_b1, f_m123, s_w

    int tid = threadIdx.x;
    int gb = blockIdx.x;

    if (gb < 256) {               // Wov = Wo @ Wv, Ksplit8 (K-slice 64)
        int ks = gb & 7;  int t = gb >> 3;      // t 0..31
        int rt = t >> 2, ct = t & 3;
        gemm_tile<128, false, 1, false>(Wo, 0, rt * 64, Wv, ct * 128,
                                        ks * 64, 4, nullptr,
                                        wp + (size_t)ks * 262144, As, Bs, tid);
        return;
    }
    if (gb < 288) {               // q = z @ Wq^T, Ksplit4 (K-slice 128)
        int t = gb - 256; int ks = t & 3; int nt = t >> 2;   // nt 0..7
        gemm_tile<64, true, 1, false>(z, 0, 0, Wq, nt * 64,
                                      ks * 128, 8, nullptr,
                                      qp + (size_t)ks * 32768, As, Bs, tid);
        return;
    }
    if (gb < 320) {               // woz = z @ Wo^T, Ksplit4
        int t = gb - 288; int ks = t & 3; int nt = t >> 2;
        gemm_tile<64, true, 1, false>(z, 0, 0, Wo, nt * 64,
                                      ks * 128, 8, nullptr,
                                      wozp + (size_t)ks * 32768, As, Bs, tid);
        return;
    }

    // ------------- mask compaction (one block per sample) -------------
    int b = gb - 320;
    if (tid == 0) { cflags[0] = 0; cflags[1] = 0; cflags[2] = 0; }
    __syncthreads();
    int lge2 = 0, lb1 = 0, lm = 0;
    for (int p = tid; p < 4096; p += 256) {
        unsigned int v = maskbytes[p];
        if (v > 1u) lge2 = 1;
        if (v != 0u) {
            if ((p & 3) == 1) lb1 = 1;
            if ((p & 3) != 0) lm = 1;
        }
    }
    if (lge2) atomicOr(&cflags[0], 1);
    if (lb1)  atomicOr(&cflags[1], 1);
    if (lm)   atomicOr(&cflags[2], 1);
    __syncthreads();
    if (tid == 0) cflags[3] = cflags[0] ? (cflags[1] ? 2 : 4) : (cflags[2] ? 1 : 4);
    __syncthreads();
    int w = cflags[3];

    int base = tid * 16;
    int cnt = 0;
    int validbits[16];
    for (int e = 0; e < 16; e++) {
        int i = base + e;
        size_t byteoff = ((size_t)b * Nn + i) * (size_t)w;
        unsigned int nz = 0;
        for (int q = 0; q < w; q++) nz |= maskbytes[byteoff + q];
        int valid = (nz == 0) ? 1 : 0;   // mask==True means padding/excluded
        validbits[e] = valid;
        cnt += valid;
    }
    scanbuf[tid] = cnt;
    __syncthreads();
    for (int off = 1; off < 256; off <<= 1) {
        int v = (tid >= off) ? scanbuf[tid - off] : 0;
        __syncthreads();
        scanbuf[tid] += v;
        __syncthreads();
    }
    int pos = scanbuf[tid] - cnt;
    for (int e = 0; e < 16; e++) {
        if (validbits[e]) { idx[b * Nn + pos] = base + e; pos++; }
    }
    if (tid == 255) nvalid[b] = scanbuf[255];
}

// ============================================================================
// kB: blocks 0..63   : qk partials qkp[8] = (sum qp) @ Wk  (Ksplit8)
//     blocks 64..319 : wov = sum of 8 wp partials
// ============================================================================
__global__ void __launch_bounds__(256) kB_qk(
    const float* __restrict__ qp, const float* __restrict__ Wk,
    const float* __restrict__ wp,
    float* __restrict__ qkp, float* __restrict__ wov)
{
    __shared__ float As[16][68];
    __shared__ float Bs[16][132];
    int tid = threadIdx.x;
    int gb = blockIdx.x;
    if (gb < 64) {
        int ks = gb & 7; int nt = gb >> 3;      // nt 0..7
        gemm_tile<64, false, 4, false>(qp, 32768, 0, Wk, nt * 64,
                                       ks * 64, 4, nullptr,
                                       qkp + (size_t)ks * 32768, As, Bs, tid);
        return;
    }
    int lin = (gb - 64) * 256 + tid;            // 0..65535 float4s
    float4 v = {0.f, 0.f, 0.f, 0.f};
    #pragma unroll
    for (int p = 0; p < 8; p++) {
        float4 w = *(const float4*)&wp[(size_t)p * 262144 + (size_t)lin * 4];
        v.x += w.x; v.y += w.y; v.z += w.z; v.w += w.w;
    }
    *(float4*)&wov[(size_t)lin * 4] = v;
}

// ============================================================================
// kE: token kernel. One block (4 waves) per (sample, segment).
// ============================================================================
__global__ void __launch_bounds__(256) kE_tokens(
    const float* __restrict__ feats, const int* __restrict__ idx,
    const int* __restrict__ nvalid, const float* __restrict__ qkp,
    float* __restrict__ s_out, float* __restrict__ den_out)
{
    __shared__ float sred[4 * Dn];
    __shared__ float dred[4];
    int tid = threadIdx.x;
    int wv = tid >> 6;
    int lane = tid & 63;
    int b = blockIdx.x / Ln;
    int l = blockIdx.x % Ln;
    int nv = nvalid[b];
    int seg_size = nv / Ln; if (seg_size < 1) seg_size = 1;
    int used = Ln * seg_size; if (used > nv) used = nv;
    int r0 = l * seg_size;
    int r1 = r0 + seg_size; if (r1 > used) r1 = used;

    // qk[l] fragment = sum of 8 K-split partials
    float4 qa = {0.f,0.f,0.f,0.f}, qb = {0.f,0.f,0.f,0.f};
    #pragma unroll
    for (int p = 0; p < 8; p++) {
        const float4* q4 = (const float4*)(qkp + (size_t)p * 32768 +
                                           (size_t)l * Dn + lane * 8);
        float4 a = q4[0], c = q4[1];
        qa.x += a.x; qa.y += a.y; qa.z += a.z; qa.w += a.w;
        qb.x += c.x; qb.y += c.y; qb.z += c.z; qb.w += c.w;
    }
    float qf[8] = {qa.x, qa.y, qa.z, qa.w, qb.x, qb.y, qb.z, qb.w};

    float sacc[8] = {0,0,0,0,0,0,0,0};
    float dacc = 0.f;
    const float inv_d = 1.0f / (float)Dn;
    const float inv_temp = 1.0f / 22.62741699796952f;  // 1/sqrt(512)

    for (int r = r0 + wv * 2; r < r1; r += 8) {
        int has2 = (r + 1 < r1);
        int t0 = idx[b * Nn + r];
        int t1 = has2 ? idx[b * Nn + r + 1] : t0;
        const float4* p0 = (const float4*)(feats + ((size_t)b * Nn + t0) * Dn + lane * 8);
        const float4* p1 = (const float4*)(feats + ((size_t)b * Nn + t1) * Dn + lane * 8);
        float4 xa0 = p0[0], xb0 = p0[1];
        float4 xa1 = p1[0], xb1 = p1[1];
        float x0[8] = {xa0.x, xa0.y, xa0.z, xa0.w, xb0.x, xb0.y, xb0.z, xb0.w};
        float x1[8] = {xa1.x, xa1.y, xa1.z, xa1.w, xb1.x, xb1.y, xb1.z, xb1.w};
        float sum0 = 0.f, ssq0 = 0.f, sum1 = 0.f, ssq1 = 0.f;
        #pragma unroll
        for (int j = 0; j < 8; j++) {
            sum0 += x0[j]; ssq0 += x0[j] * x0[j];
            sum1 += x1[j]; ssq1 += x1[j] * x1[j];
        }
        #pragma unroll
        for (int off = 32; off > 0; off >>= 1) {
            sum0 += __shfl_xor(sum0, off);
            ssq0 += __shfl_xor(ssq0, off);
            sum1 += __shfl_xor(sum1, off);
            ssq1 += __shfl_xor(ssq1, off);
        }
        float mu0 = sum0 * inv_d, mu1 = sum1 * inv_d;
        float rstd0 = rsqrtf(ssq0 * inv_d - mu0 * mu0 + 1e-5f);
        float rstd1 = rsqrtf(ssq1 * inv_d - mu1 * mu1 + 1e-5f);
        float ln0[8], ln1[8];
        float dot0 = 0.f, dot1 = 0.f;
        #pragma unroll
        for (int j = 0; j < 8; j++) {
            ln0[j] = (x0[j] - mu0) * rstd0; dot0 += ln0[j] * qf[j];
            ln1[j] = (x1[j] - mu1) * rstd1; dot1 += ln1[j] * qf[j];
        }
        #pragma unroll
        for (int off = 32; off > 0; off >>= 1) {
            dot0 += __shfl_xor(dot0, off);
            dot1 += __shfl_xor(dot1, off);
        }
        float lg0 = fminf(5.0f, fmaxf(-5.0f, dot0 * inv_temp));
        float lg1 = fminf(5.0f, fmaxf(-5.0f, dot1 * inv_temp));
        float e0 = expf(lg0);
        float e1 = has2 ? expf(lg1) : 0.f;
        #pragma unroll
        for (int j = 0; j < 8; j++) sacc[j] += e0 * ln0[j] + e1 * ln1[j];
        dacc += e0 + e1;
    }

    #pragma unroll
    for (int j = 0; j < 8; j++) sred[wv * Dn + lane * 8 + j] = sacc[j];
    if (lane == 0) dred[wv] = dacc;
    __syncthreads();
    for (int e = tid; e < Dn; e += 256) {
        float v = sred[e] + sred[Dn + e] + sred[2 * Dn + e] + sred[3 * Dn + e];
        s_out[(size_t)blockIdx.x * Dn + e] = v;
    }
    if (tid == 0) den_out[blockIdx.x] = dred[0] + dred[1] + dred[2] + dred[3];
}

// ============================================================================
// kG: out partials op[8] = (s/den) @ wov^T   (64x128 tiles, Ksplit8)
// ============================================================================
__global__ void __launch_bounds__(256) kG_gemm(
    const float* __restrict__ s, const float* __restrict__ den,
    const float* __restrict__ wov, float* __restrict__ op)
{
    __shared__ float As[16][68];
    __shared__ float Bs[16][132];
    __shared__ float ssv[64];
    int tid = threadIdx.x;
    int gb = blockIdx.x;
    int ks = gb & 7; int t = gb >> 3;
    int rt = t >> 2, ct = t & 3;
    int m0 = rt * 64;
    if (tid < 64) {
        float dv = den[m0 + tid];
        ssv[tid] = (dv > 0.f) ? 1.f / dv : 0.f;
    }
    __syncthreads();
    gemm_tile<128, true, 1, true>(s, 0, m0, wov, ct * 128,
                                  ks * 64, 4, ssv,
                                  op + (size_t)ks * 262144, As, Bs, tid);
}

// ============================================================================
// kH: out = select(nvalid==0 -> z; den>0 -> sum op + bo; else -> sum wozp + bo)
// ============================================================================
__global__ void __launch_bounds__(256) kH_epilogue(
    const float* __restrict__ op, const float* __restrict__ den,
    const int* __restrict__ nvalid, const float* __restrict__ wozp,
    const float* __restrict__ z, const float* __restrict__ bo,
    float* __restrict__ out)
{
    int lin = blockIdx.x * 256 + threadIdx.x;   // 65536 float4s
    int row = lin >> 7;
    int col = (lin & 127) * 4;
    int b = row >> 6, l = row & 63;
    float4 v;
    if (nvalid[b] == 0) {
        v = *(const float4*)&z[(size_t)l * Dn + col];
    } else {
        float4 bv = *(const float4*)&bo[col];
        float dv = den[row];
        if (dv > 0.f) {
            float4 a = {0.f, 0.f, 0.f, 0.f};
            #pragma unroll
            for (int p = 0; p < 8; p++) {
                float4 w = *(const float4*)&op[(size_t)p * 262144 + (size_t)row * Dn + col];
                a.x += w.x; a.y += w.y; a.z += w.z; a.w += w.w;
            }
            v.x = a.x + bv.x; v.y = a.y + bv.y; v.z = a.z + bv.z; v.w = a.w + bv.w;
        } else {
            float4 a = {0.f, 0.f, 0.f, 0.f};
            #pragma unroll
            for (int p = 0; p < 4; p++) {
                float4 w = *(const float4*)&wozp[(size_t)p * 32768 + (size_t)l * Dn + col];
                a.x += w.x; a.y += w.y; a.z += w.z; a.w += w.w;
            }
            v.x = a.x + bv.x; v.y = a.y + bv.y; v.z = a.z + bv.z; v.w = a.w + bv.w;
        }
    }
    *(float4*)&out[(size_t)row * Dn + col] = v;
}

extern "C" void kernel_launch(void* const* d_in, const int* in_sizes, int n_in,
                              void* d_out, int out_size, void* d_ws, size_t ws_size,
                              hipStream_t stream) {
    const float* feats = (const float*)d_in[0];
    // d_in[1] = coords: unused by the reference
    const unsigned char* maskb = (const unsigned char*)d_in[2];
    const float* z  = (const float*)d_in[3];
    const float* Wq = (const float*)d_in[4];
    const float* Wk = (const float*)d_in[5];
    const float* Wv = (const float*)d_in[6];
    const float* Wo = (const float*)d_in[7];
    const float* bo = (const float*)d_in[8];
    float* out = (float*)d_out;

    int*   nvalid = (int*)d_ws;
    int*   idx    = nvalid + 64;
    float* fbase  = (float*)(idx + Bn * Nn);
    float* qp     = fbase;                 // 4 x 32768
    float* wozp   = qp   + 4 * 32768;      // 4 x 32768
    float* qkp    = wozp + 4 * 32768;      // 8 x 32768
    float* wov    = qkp  + 8 * 32768;      // 262144
    float* sbuf   = wov  + 262144;         // 262144
    float* den    = sbuf + 262144;         // 1024 (padded)
    float* wp     = den  + 1024;           // 8 x 262144
    float* op     = wp;                    // alias: wp consumed by kB before kG writes op

    kA_prep<<<328, 256, 0, stream>>>(Wo, Wv, z, Wq, maskb, wp, qp, wozp, nvalid, idx);
    kB_qk<<<320, 256, 0, stream>>>(qp, Wk, wp, qkp, wov);
    kE_tokens<<<Bn * Ln, 256, 0, stream>>>(feats, idx, nvalid, qkp, sbuf, den);
    kG_gemm<<<256, 256, 0, stream>>>(sbuf, den, wov, op);
    kH_epilogue<<<256, 256, 0, stream>>>(op, den, nvalid, wozp, z, bo, out);
}